// Round 6
// baseline (348.265 us; speedup 1.0000x reference)
//
#include <hip/hip_runtime.h>
#include <cstdint>
#include <cstddef>

// ============================================================================
// CellSetAttentionNetwork: X[8,2048,512] fp32, single-head attention D=H=512.
// Pipeline: cvt(all) -> QKV gemm -> scores gemm (exp + rowsum fused) ->
//           PV gemm (1/rowsum fused) -> out gemm -> layernorm.
// GEMMs: bf16 MFMA 16x16x32, BMxBN tile (4 waves, wave tile BM/2 x BN/2),
// BK=64 as two [rows][32] LDS halves (per-half layout = verified structure).
// R5 evidence: scores 75us with MfmaUtil 13%/VALU 24%/HBM 21% -> latency
// bound; widen BN to 256 so each wave runs 64 MFMA per barrier-pair (2x).
// Softmax is max-free: scores stores E=exp(s*scale) + rowsum atomics; PV
// divides by rowsum.
//
// ws layout (byte offsets):
//   [0, 64M)      S/E [8][2048][2048] bf16
//   [0, 16M)      Xb  [16384][512] bf16 (overlay: dead before S written)
//   [64M, +2M)    Wt  [2048][512] bf16 (Wq^T,Wk^T,Wv^T,Wo^T stacked)
//   [66M, +16M)   q   [16384][512] bf16; reused as ctx after scores gemm
//   [82M, +16M)   k   [16384][512] bf16
//   [98M, +16M)   vT  [8][512][2048] bf16
//   [114M, +64K)  rowsum fp32[16384]
// ============================================================================

typedef __bf16 bf16x8 __attribute__((ext_vector_type(8)));
typedef float  f32x4  __attribute__((ext_vector_type(4)));

__device__ __forceinline__ uint16_t f2bf(float f) {
  union { float f; uint32_t u; } v; v.f = f;
  uint32_t r = v.u + 0x7FFFu + ((v.u >> 16) & 1u);   // RNE
  return (uint16_t)(r >> 16);
}

__device__ __forceinline__ void gld16(const uint16_t* g, uint16_t* l) {
  // async global->LDS, 16B per lane; LDS dest = wave-uniform base + lane*16
  __builtin_amdgcn_global_load_lds(
      (__attribute__((address_space(1))) void*)(g),
      (__attribute__((address_space(3))) void*)(l), 16, 0, 0);
}

// MODE 0: QKV   (out q, k normal [M][512]; v transposed vT[b][h][t], +bias)
// MODE 1: scores (out bf16 E=exp(s*scale), rowsum atomics), batch = blockIdx.z
// MODE 2: ctx = (E @ vT^T)/rowsum  (out bf16 [b*2048+n][512]), batch = blockIdx.z
// MODE 3: out-proj (+bo +X residual, fp32 out)
// BM/BN: tile dims; 4 waves in 2x2 grid, wave tile (BM/2)x(BN/2); K % 64 == 0.
template <int MODE, int BM, int BN>
__global__ __launch_bounds__(256, 2) void gemm_k(
    const uint16_t* __restrict__ A, const uint16_t* __restrict__ Bt,
    void* __restrict__ OutA, uint16_t* __restrict__ OutK,
    uint16_t* __restrict__ OutVT, float* __restrict__ rsum, int K, int lda,
    int ldb, const float* __restrict__ b0, const float* __restrict__ b1,
    const float* __restrict__ b2, const float* __restrict__ Xres, float scale) {
  constexpr int MT = BM / 32;               // acc tiles per wave, m dim
  constexpr int NT = BN / 32;               // acc tiles per wave, n dim
  constexpr int AI = BM / 64;               // A gld16 issues per half per wave
  constexpr int BI = BN / 64;               // B gld16 issues per half per wave
  // two BK=32 halves, each with the proven [rows][32] layout
  __shared__ alignas(16) uint16_t As[2 * BM * 32];
  __shared__ alignas(16) uint16_t Bs[2 * BN * 32];

  const int tid = threadIdx.x;
  const int w = tid >> 6, lane = tid & 63;
  const int wm = w >> 1, wn = w & 1;        // 2x2 wave grid
  const int m0 = blockIdx.y * BM, n0 = blockIdx.x * BN;
  const int z = blockIdx.z;

  const uint16_t* Ab = A;
  const uint16_t* Bb = Bt;
  if (MODE == 1) { Ab += (size_t)z * 2048 * 512;  Bb += (size_t)z * 2048 * 512; }
  if (MODE == 2) { Ab += (size_t)z * 2048 * 2048; Bb += (size_t)z * 512 * 2048; }

  // staging: one gld16 by a full wave covers 16 rows x 32 k (64 lanes x 16B)
  const int kc = (lane & 3) * 8;            // k offset within a 32-half
  const int rbaseA = w * (BM / 4);
  const int rbaseB = w * (BN / 4);
  const uint16_t* gA = Ab + (size_t)(m0 + rbaseA + (lane >> 2)) * lda + kc;
  const uint16_t* gB = Bb + (size_t)(n0 + rbaseB + (lane >> 2)) * ldb + kc;
  uint16_t* lA0 = &As[rbaseA * 32];
  uint16_t* lB0 = &Bs[rbaseB * 32];

  f32x4 acc[MT][NT];
#pragma unroll
  for (int i = 0; i < MT; i++)
#pragma unroll
    for (int j = 0; j < NT; j++) acc[i][j] = (f32x4){0.f, 0.f, 0.f, 0.f};

  const int lr = lane & 15;
  const int q8 = (lane >> 4) * 8;

  for (int k0 = 0; k0 < K; k0 += 64) {
#pragma unroll
    for (int h = 0; h < 2; h++) {
#pragma unroll
      for (int j = 0; j < AI; j++)
        gld16(gA + k0 + h * 32 + (size_t)(j * 16) * lda,
              lA0 + h * BM * 32 + j * 16 * 32);
#pragma unroll
      for (int j = 0; j < BI; j++)
        gld16(gB + k0 + h * 32 + (size_t)(j * 16) * ldb,
              lB0 + h * BN * 32 + j * 16 * 32);
    }
    __syncthreads();   // compiler drains vmcnt(0) before s_barrier
#pragma unroll
    for (int h = 0; h < 2; h++) {
      bf16x8 af[MT], bfr[NT];
#pragma unroll
      for (int t = 0; t < MT; t++)
        af[t] = *(const bf16x8*)
            &As[h * BM * 32 + (wm * (BM / 2) + t * 16 + lr) * 32 + q8];
#pragma unroll
      for (int t = 0; t < NT; t++)
        bfr[t] = *(const bf16x8*)
            &Bs[h * BN * 32 + (wn * (BN / 2) + t * 16 + lr) * 32 + q8];
#pragma unroll
      for (int nt = 0; nt < NT; nt++)
#pragma unroll
        for (int mt = 0; mt < MT; mt++)
          acc[mt][nt] = __builtin_amdgcn_mfma_f32_16x16x32_bf16(
              af[mt], bfr[nt], acc[mt][nt], 0, 0, 0);
    }
    __syncthreads();   // protect LDS before next-iter staging
  }

  // epilogue: C/D layout col=lane&15, row=quad*4+reg  (m89/m91 verified)
  if (MODE == 1) {
    // store E = exp(s*scale); accumulate row sums (quad's 16 lanes share rows)
    uint16_t* Sp = (uint16_t*)OutA + (size_t)z * 2048 * 2048;
#pragma unroll
    for (int mt = 0; mt < MT; mt++) {
      float rp[4] = {0.f, 0.f, 0.f, 0.f};
#pragma unroll
      for (int nt = 0; nt < NT; nt++) {
#pragma unroll
        for (int i = 0; i < 4; i++) {
          const int row = m0 + wm * (BM / 2) + mt * 16 + (lane >> 4) * 4 + i;
          const int col = n0 + wn * (BN / 2) + nt * 16 + lr;
          const float e = __expf(acc[mt][nt][i] * scale);
          Sp[(size_t)row * 2048 + col] = f2bf(e);
          rp[i] += e;
        }
      }
#pragma unroll
      for (int i = 0; i < 4; i++) {
        float p = rp[i];
        p += __shfl_xor(p, 1); p += __shfl_xor(p, 2);
        p += __shfl_xor(p, 4); p += __shfl_xor(p, 8);
        if (lr == 0) {
          const int row = m0 + wm * (BM / 2) + mt * 16 + (lane >> 4) * 4 + i;
          atomicAdd(&rsum[z * 2048 + row], p);
        }
      }
    }
  } else if (MODE == 2) {
#pragma unroll
    for (int mt = 0; mt < MT; mt++) {
#pragma unroll
      for (int i = 0; i < 4; i++) {
        const int row = m0 + wm * (BM / 2) + mt * 16 + (lane >> 4) * 4 + i;
        const float sc = 1.0f / rsum[z * 2048 + row];
#pragma unroll
        for (int nt = 0; nt < NT; nt++) {
          const int col = n0 + wn * (BN / 2) + nt * 16 + lr;
          ((uint16_t*)OutA)[((size_t)z * 2048 + row) * 512 + col] =
              f2bf(acc[mt][nt][i] * sc);
        }
      }
    }
  } else {
#pragma unroll
    for (int mt = 0; mt < MT; mt++) {
#pragma unroll
      for (int nt = 0; nt < NT; nt++) {
#pragma unroll
        for (int i = 0; i < 4; i++) {
          const int row = m0 + wm * (BM / 2) + mt * 16 + (lane >> 4) * 4 + i;
          const int col = n0 + wn * (BN / 2) + nt * 16 + lr;
          const float v = acc[mt][nt][i];
          if (MODE == 0) {
            const int which = col >> 9, c = col & 511;
            if (which == 0) {
              ((uint16_t*)OutA)[(size_t)row * 512 + c] = f2bf(v + b0[c]);
            } else if (which == 1) {
              OutK[(size_t)row * 512 + c] = f2bf(v + b1[c]);
            } else {  // v -> transposed vT[b][h][t]
              OutVT[(size_t)(row >> 11) * (512 * 2048) + (size_t)c * 2048 +
                    (row & 2047)] = f2bf(v + b2[c]);
            }
          } else {  // MODE 3
            const size_t idx = (size_t)row * 512 + col;
            ((float*)OutA)[idx] = v + b0[col] + Xres[idx];
          }
        }
      }
    }
  }
}

// Fused conversions: X fp32->bf16 (8.39M elems, 4/thread), Wt transpose
// (first 1.05M threads), rowsum zeroing (first 16384 threads).
__global__ __launch_bounds__(256) void cvt_all_k(
    const float* __restrict__ X, uint16_t* __restrict__ Xb,
    const float* __restrict__ Wq, const float* __restrict__ Wk,
    const float* __restrict__ Wv, const float* __restrict__ Wo,
    uint16_t* __restrict__ Wt, float* __restrict__ rsum) {
  const int i = blockIdx.x * 256 + threadIdx.x;   // 0..2097151
  const float4 f = ((const float4*)X)[i];
  uint32_t lo = (uint32_t)f2bf(f.x) | ((uint32_t)f2bf(f.y) << 16);
  uint32_t hi = (uint32_t)f2bf(f.z) | ((uint32_t)f2bf(f.w) << 16);
  ((uint2*)Xb)[i] = make_uint2(lo, hi);
  if (i < 16384) rsum[i] = 0.f;
  if (i < 2048 * 512) {   // Wt[n][k] = W[k][n&511]
    const int n = i >> 9, kk = i & 511;
    const int which = n >> 9, c = n & 511;
    const float* W =
        (which == 0) ? Wq : (which == 1) ? Wk : (which == 2) ? Wv : Wo;
    Wt[i] = f2bf(W[kk * 512 + c]);
  }
}

// in-place layernorm, wave per row of 512 fp32
__global__ __launch_bounds__(256) void ln_k(float* __restrict__ O,
                                            const float* __restrict__ g,
                                            const float* __restrict__ b) {
  const int tid = threadIdx.x, w = tid >> 6, lane = tid & 63;
  float* p = O + ((size_t)blockIdx.x * 4 + w) * 512;
  float4 v0 = ((const float4*)p)[lane];
  float4 v1 = ((const float4*)p)[64 + lane];
  float s  = v0.x + v0.y + v0.z + v0.w + v1.x + v1.y + v1.z + v1.w;
  float sq = v0.x * v0.x + v0.y * v0.y + v0.z * v0.z + v0.w * v0.w +
             v1.x * v1.x + v1.y * v1.y + v1.z * v1.z + v1.w * v1.w;
#pragma unroll
  for (int off = 32; off >= 1; off >>= 1) {
    s += __shfl_xor(s, off);
    sq += __shfl_xor(sq, off);
  }
  const float mean = s * (1.f / 512.f);
  const float var = sq * (1.f / 512.f) - mean * mean;  // population var (jnp.var)
  const float rstd = rsqrtf(var + 1e-5f);
  const float4 g0 = ((const float4*)g)[lane], g1 = ((const float4*)g)[64 + lane];
  const float4 b0 = ((const float4*)b)[lane], b1 = ((const float4*)b)[64 + lane];
  v0.x = (v0.x - mean) * rstd * g0.x + b0.x;
  v0.y = (v0.y - mean) * rstd * g0.y + b0.y;
  v0.z = (v0.z - mean) * rstd * g0.z + b0.z;
  v0.w = (v0.w - mean) * rstd * g0.w + b0.w;
  v1.x = (v1.x - mean) * rstd * g1.x + b1.x;
  v1.y = (v1.y - mean) * rstd * g1.y + b1.y;
  v1.z = (v1.z - mean) * rstd * g1.z + b1.z;
  v1.w = (v1.w - mean) * rstd * g1.w + b1.w;
  ((float4*)p)[lane] = v0;
  ((float4*)p)[64 + lane] = v1;
}

extern "C" void kernel_launch(void* const* d_in, const int* in_sizes, int n_in,
                              void* d_out, int out_size, void* d_ws,
                              size_t ws_size, hipStream_t stream) {
  const float* X     = (const float*)d_in[0];
  const float* Wq    = (const float*)d_in[1];
  const float* bq    = (const float*)d_in[2];
  const float* Wk    = (const float*)d_in[3];
  const float* bk    = (const float*)d_in[4];
  const float* Wv    = (const float*)d_in[5];
  const float* bv    = (const float*)d_in[6];
  const float* Wo    = (const float*)d_in[7];
  const float* bo    = (const float*)d_in[8];
  const float* gamma = (const float*)d_in[9];
  const float* beta  = (const float*)d_in[10];
  float* out = (float*)d_out;

  char* ws = (char*)d_ws;   // ~114.1 MB used (overlaid layout, see header)
  uint16_t* S    = (uint16_t*)(ws);                 // [0, 64M)
  uint16_t* Xb   = (uint16_t*)(ws);                 // [0, 16M) overlay on S
  uint16_t* Wt   = (uint16_t*)(ws + 67108864);      // [64M, 66M)
  uint16_t* q    = (uint16_t*)(ws + 69206016);      // [66M, 82M), later ctx
  uint16_t* kb   = (uint16_t*)(ws + 85983232);      // [82M, 98M)
  uint16_t* vT   = (uint16_t*)(ws + 102760448);     // [98M, 114M) [8][512][2048]
  float*    rsum = (float*)(ws + 119537664);        // [114M, +64K) fp32[16384]
  uint16_t* ctx  = q;                               // overlay: q dead after scores

  cvt_all_k<<<dim3(8192), dim3(256), 0, stream>>>(X, Xb, Wq, Wk, Wv, Wo, Wt,
                                                  rsum);
  // QKV: M=16384, N=1536, K=512, tile 128x256 -> grid 768
  gemm_k<0, 128, 256><<<dim3(6, 128, 1), dim3(256), 0, stream>>>(
      Xb, Wt, (void*)q, kb, vT, nullptr, 512, 512, 512, bq, bk, bv, nullptr,
      1.f);
  // scores: per batch M=N=2048, K=512; E=exp(s/sqrt(512)) + rowsum atomics
  gemm_k<1, 128, 256><<<dim3(8, 16, 8), dim3(256), 0, stream>>>(
      q, kb, (void*)S, nullptr, nullptr, rsum, 512, 512, 512, nullptr, nullptr,
      nullptr, nullptr, 0.044194173824159216f);
  // ctx = (E @ V)/rowsum: per batch M=2048, N=512, K=2048, tile 64x256
  gemm_k<2, 64, 256><<<dim3(2, 32, 8), dim3(256), 0, stream>>>(
      S, vT, (void*)ctx, nullptr, nullptr, rsum, 2048, 2048, 2048, nullptr,
      nullptr, nullptr, nullptr, 1.f);
  // out = ctx @ Wo + bo + X: M=16384, N=512, K=512, tile 128x128 (R3-proven)
  gemm_k<3, 128, 128><<<dim3(4, 128, 1), dim3(256), 0, stream>>>(
      ctx, Wt + 1536 * 512, (void*)out, nullptr, nullptr, nullptr, 512, 512,
      512, bo, nullptr, nullptr, X, 1.f);
  ln_k<<<dim3(4096), dim3(256), 0, stream>>>(out, gamma, beta);
}

// Round 7
// 327.854 us; speedup vs baseline: 1.0623x; 1.0623x over previous
//
#include <hip/hip_runtime.h>
#include <cstdint>
#include <cstddef>

// ============================================================================
// CellSetAttentionNetwork: X[8,2048,512] fp32, single-head attention D=H=512.
// Pipeline: cvt(all) -> QKV gemm -> scores gemm (exp + rowsum fused) ->
//           PV gemm (1/rowsum fused) -> out gemm -> layernorm.
// GEMMs: bf16 MFMA 16x16x32, BMxBN tile (2x2 waves), BK=32, *software
// pipelined* K-loop: 3 LDS buffers, depth-2 global_load_lds prefetch kept in
// flight ACROSS barriers via bare s_barrier + manual s_waitcnt vmcnt(PW)
// (AITER-style; __syncthreads would force a vmcnt(0) drain every iter, which
// R2-R6 counters showed to be the bottleneck: MfmaUtil 13%, VALU 24%, HBM 21%
// -> all idle).  R6 lesson: 48KB+ tiles tanked occupancy (m132-style); tile
// shapes stay at the proven 128x128 (QKV/scores/OP) and 64x128 (PV).
// Softmax is max-free: scores stores E=exp(s*scale) + rowsum atomics; PV
// divides by rowsum.
//
// ws layout (byte offsets):
//   [0, 64M)      S/E [8][2048][2048] bf16
//   [0, 16M)      Xb  [16384][512] bf16 (overlay: dead before S written)
//   [64M, +2M)    Wt  [2048][512] bf16 (Wq^T,Wk^T,Wv^T,Wo^T stacked)
//   [66M, +16M)   q   [16384][512] bf16; reused as ctx after scores gemm
//   [82M, +16M)   k   [16384][512] bf16
//   [98M, +16M)   vT  [8][512][2048] bf16
//   [114M, +64K)  rowsum fp32[16384]
// ============================================================================

typedef __bf16 bf16x8 __attribute__((ext_vector_type(8)));
typedef float  f32x4  __attribute__((ext_vector_type(4)));

__device__ __forceinline__ uint16_t f2bf(float f) {
  union { float f; uint32_t u; } v; v.f = f;
  uint32_t r = v.u + 0x7FFFu + ((v.u >> 16) & 1u);   // RNE
  return (uint16_t)(r >> 16);
}

__device__ __forceinline__ void gld16(const uint16_t* g, uint16_t* l) {
  // async global->LDS, 16B per lane; LDS dest = wave-uniform base + lane*16
  __builtin_amdgcn_global_load_lds(
      (__attribute__((address_space(1))) void*)(g),
      (__attribute__((address_space(3))) void*)(l), 16, 0, 0);
}

// MODE 0: QKV   (out q, k normal [M][512]; v transposed vT[b][h][t], +bias)
// MODE 1: scores (out bf16 E=exp(s*scale), rowsum atomics), batch = blockIdx.z
// MODE 2: ctx = (E @ vT^T)/rowsum  (out bf16 [b*2048+n][512]), batch = blockIdx.z
// MODE 3: out-proj (+bo +X residual, fp32 out)
// BM/BN: tile dims; 4 waves in 2x2 grid, wave tile (BM/2)x(BN/2); K % 32 == 0,
// K/32 >= 2.
template <int MODE, int BM, int BN>
__global__ __launch_bounds__(256, 2) void gemm_k(
    const uint16_t* __restrict__ A, const uint16_t* __restrict__ Bt,
    void* __restrict__ OutA, uint16_t* __restrict__ OutK,
    uint16_t* __restrict__ OutVT, float* __restrict__ rsum, int K, int lda,
    int ldb, const float* __restrict__ b0, const float* __restrict__ b1,
    const float* __restrict__ b2, const float* __restrict__ Xres, float scale) {
  constexpr int MT = BM / 32;      // acc tiles per wave, m dim
  constexpr int NT = BN / 32;      // acc tiles per wave, n dim
  constexpr int AI = BM / 64;      // A gld16 issues per wave per k-tile
  constexpr int BI = BN / 64;      // B gld16 issues per wave per k-tile
  constexpr int PW = AI + BI;      // this wave's loads per k-tile (vmcnt unit)
  __shared__ alignas(16) uint16_t As[3][BM * 32];
  __shared__ alignas(16) uint16_t Bs[3][BN * 32];

  const int tid = threadIdx.x;
  const int w = tid >> 6, lane = tid & 63;
  const int wm = w >> 1, wn = w & 1;        // 2x2 wave grid
  const int m0 = blockIdx.y * BM, n0 = blockIdx.x * BN;
  const int z = blockIdx.z;

  const uint16_t* Ab = A;
  const uint16_t* Bb = Bt;
  if (MODE == 1) { Ab += (size_t)z * 2048 * 512;  Bb += (size_t)z * 2048 * 512; }
  if (MODE == 2) { Ab += (size_t)z * 2048 * 2048; Bb += (size_t)z * 512 * 2048; }

  // staging addresses: one gld16 by a full wave covers 16 rows x 32 k
  const int kc = (lane & 3) * 8;            // k offset within a 32-tile
  const int rbA = w * (BM / 4);             // this wave's A row base
  const int rbB = w * (BN / 4);             // this wave's B row base
  const uint16_t* gA = Ab + (size_t)(m0 + rbA + (lane >> 2)) * lda + kc;
  const uint16_t* gB = Bb + (size_t)(n0 + rbB + (lane >> 2)) * ldb + kc;

  f32x4 acc[MT][NT];
#pragma unroll
  for (int i = 0; i < MT; i++)
#pragma unroll
    for (int j = 0; j < NT; j++) acc[i][j] = (f32x4){0.f, 0.f, 0.f, 0.f};

  const int lr = lane & 15;
  const int q8 = (lane >> 4) * 8;
  const int iters = K >> 5;

  // stage k-tile `t` into buffer `buf` (PW gld16 issues by this wave)
  auto stage = [&](int t, int buf) {
    const int k0 = t * 32;
#pragma unroll
    for (int j = 0; j < AI; j++)
      gld16(gA + k0 + (size_t)(j * 16) * lda, &As[buf][(rbA + j * 16) * 32]);
#pragma unroll
    for (int j = 0; j < BI; j++)
      gld16(gB + k0 + (size_t)(j * 16) * ldb, &Bs[buf][(rbB + j * 16) * 32]);
  };

  auto compute = [&](int buf) {
    bf16x8 af[MT], bfr[NT];
#pragma unroll
    for (int t = 0; t < MT; t++)
      af[t] = *(const bf16x8*)&As[buf][(wm * (BM / 2) + t * 16 + lr) * 32 + q8];
#pragma unroll
    for (int t = 0; t < NT; t++)
      bfr[t] = *(const bf16x8*)&Bs[buf][(wn * (BN / 2) + t * 16 + lr) * 32 + q8];
#pragma unroll
    for (int nt = 0; nt < NT; nt++)
#pragma unroll
      for (int mt = 0; mt < MT; mt++)
        acc[mt][nt] = __builtin_amdgcn_mfma_f32_16x16x32_bf16(
            af[mt], bfr[nt], acc[mt][nt], 0, 0, 0);
  };

  // ---- depth-2 pipelined K-loop: loads stay in flight across barriers ----
  stage(0, 0);
  stage(1, 1);
  int buf = 0;
  for (int i = 0; i < iters - 1; ++i) {
    // wait for tile i only (tile i+1's PW loads remain outstanding)
    asm volatile("s_waitcnt vmcnt(%0)" ::"i"(PW) : "memory");
    __builtin_amdgcn_s_barrier();   // tile i visible to all; buf of tile i-1 free
    if (i + 2 < iters) stage(i + 2, (buf + 2 >= 3) ? buf - 1 : buf + 2);
    compute(buf);
    buf = (buf == 2) ? 0 : buf + 1;
  }
  asm volatile("s_waitcnt vmcnt(0)" ::: "memory");
  __builtin_amdgcn_s_barrier();
  compute(buf);

  // epilogue: C/D layout col=lane&15, row=quad*4+reg  (m89/m91 verified)
  if (MODE == 1) {
    // store E = exp(s*scale); accumulate row sums (quad's 16 lanes share rows)
    uint16_t* Sp = (uint16_t*)OutA + (size_t)z * 2048 * 2048;
#pragma unroll
    for (int mt = 0; mt < MT; mt++) {
      float rp[4] = {0.f, 0.f, 0.f, 0.f};
#pragma unroll
      for (int nt = 0; nt < NT; nt++) {
#pragma unroll
        for (int i = 0; i < 4; i++) {
          const int row = m0 + wm * (BM / 2) + mt * 16 + (lane >> 4) * 4 + i;
          const int col = n0 + wn * (BN / 2) + nt * 16 + lr;
          const float e = __expf(acc[mt][nt][i] * scale);
          Sp[(size_t)row * 2048 + col] = f2bf(e);
          rp[i] += e;
        }
      }
#pragma unroll
      for (int i = 0; i < 4; i++) {
        float p = rp[i];
        p += __shfl_xor(p, 1); p += __shfl_xor(p, 2);
        p += __shfl_xor(p, 4); p += __shfl_xor(p, 8);
        if (lr == 0) {
          const int row = m0 + wm * (BM / 2) + mt * 16 + (lane >> 4) * 4 + i;
          atomicAdd(&rsum[z * 2048 + row], p);
        }
      }
    }
  } else if (MODE == 2) {
#pragma unroll
    for (int mt = 0; mt < MT; mt++) {
#pragma unroll
      for (int i = 0; i < 4; i++) {
        const int row = m0 + wm * (BM / 2) + mt * 16 + (lane >> 4) * 4 + i;
        const float sc = 1.0f / rsum[z * 2048 + row];
#pragma unroll
        for (int nt = 0; nt < NT; nt++) {
          const int col = n0 + wn * (BN / 2) + nt * 16 + lr;
          ((uint16_t*)OutA)[((size_t)z * 2048 + row) * 512 + col] =
              f2bf(acc[mt][nt][i] * sc);
        }
      }
    }
  } else {
#pragma unroll
    for (int mt = 0; mt < MT; mt++) {
#pragma unroll
      for (int nt = 0; nt < NT; nt++) {
#pragma unroll
        for (int i = 0; i < 4; i++) {
          const int row = m0 + wm * (BM / 2) + mt * 16 + (lane >> 4) * 4 + i;
          const int col = n0 + wn * (BN / 2) + nt * 16 + lr;
          const float v = acc[mt][nt][i];
          if (MODE == 0) {
            const int which = col >> 9, c = col & 511;
            if (which == 0) {
              ((uint16_t*)OutA)[(size_t)row * 512 + c] = f2bf(v + b0[c]);
            } else if (which == 1) {
              OutK[(size_t)row * 512 + c] = f2bf(v + b1[c]);
            } else {  // v -> transposed vT[b][h][t]
              OutVT[(size_t)(row >> 11) * (512 * 2048) + (size_t)c * 2048 +
                    (row & 2047)] = f2bf(v + b2[c]);
            }
          } else {  // MODE 3
            const size_t idx = (size_t)row * 512 + col;
            ((float*)OutA)[idx] = v + b0[col] + Xres[idx];
          }
        }
      }
    }
  }
}

// Fused conversions: X fp32->bf16 (8.39M elems, 4/thread), Wt transpose
// (first 1.05M threads), rowsum zeroing (first 16384 threads).
__global__ __launch_bounds__(256) void cvt_all_k(
    const float* __restrict__ X, uint16_t* __restrict__ Xb,
    const float* __restrict__ Wq, const float* __restrict__ Wk,
    const float* __restrict__ Wv, const float* __restrict__ Wo,
    uint16_t* __restrict__ Wt, float* __restrict__ rsum) {
  const int i = blockIdx.x * 256 + threadIdx.x;   // 0..2097151
  const float4 f = ((const float4*)X)[i];
  uint32_t lo = (uint32_t)f2bf(f.x) | ((uint32_t)f2bf(f.y) << 16);
  uint32_t hi = (uint32_t)f2bf(f.z) | ((uint32_t)f2bf(f.w) << 16);
  ((uint2*)Xb)[i] = make_uint2(lo, hi);
  if (i < 16384) rsum[i] = 0.f;
  if (i < 2048 * 512) {   // Wt[n][k] = W[k][n&511]
    const int n = i >> 9, kk = i & 511;
    const int which = n >> 9, c = n & 511;
    const float* W =
        (which == 0) ? Wq : (which == 1) ? Wk : (which == 2) ? Wv : Wo;
    Wt[i] = f2bf(W[kk * 512 + c]);
  }
}

// in-place layernorm, wave per row of 512 fp32
__global__ __launch_bounds__(256) void ln_k(float* __restrict__ O,
                                            const float* __restrict__ g,
                                            const float* __restrict__ b) {
  const int tid = threadIdx.x, w = tid >> 6, lane = tid & 63;
  float* p = O + ((size_t)blockIdx.x * 4 + w) * 512;
  float4 v0 = ((const float4*)p)[lane];
  float4 v1 = ((const float4*)p)[64 + lane];
  float s  = v0.x + v0.y + v0.z + v0.w + v1.x + v1.y + v1.z + v1.w;
  float sq = v0.x * v0.x + v0.y * v0.y + v0.z * v0.z + v0.w * v0.w +
             v1.x * v1.x + v1.y * v1.y + v1.z * v1.z + v1.w * v1.w;
#pragma unroll
  for (int off = 32; off >= 1; off >>= 1) {
    s += __shfl_xor(s, off);
    sq += __shfl_xor(sq, off);
  }
  const float mean = s * (1.f / 512.f);
  const float var = sq * (1.f / 512.f) - mean * mean;  // population var (jnp.var)
  const float rstd = rsqrtf(var + 1e-5f);
  const float4 g0 = ((const float4*)g)[lane], g1 = ((const float4*)g)[64 + lane];
  const float4 b0 = ((const float4*)b)[lane], b1 = ((const float4*)b)[64 + lane];
  v0.x = (v0.x - mean) * rstd * g0.x + b0.x;
  v0.y = (v0.y - mean) * rstd * g0.y + b0.y;
  v0.z = (v0.z - mean) * rstd * g0.z + b0.z;
  v0.w = (v0.w - mean) * rstd * g0.w + b0.w;
  v1.x = (v1.x - mean) * rstd * g1.x + b1.x;
  v1.y = (v1.y - mean) * rstd * g1.y + b1.y;
  v1.z = (v1.z - mean) * rstd * g1.z + b1.z;
  v1.w = (v1.w - mean) * rstd * g1.w + b1.w;
  ((float4*)p)[lane] = v0;
  ((float4*)p)[64 + lane] = v1;
}

extern "C" void kernel_launch(void* const* d_in, const int* in_sizes, int n_in,
                              void* d_out, int out_size, void* d_ws,
                              size_t ws_size, hipStream_t stream) {
  const float* X     = (const float*)d_in[0];
  const float* Wq    = (const float*)d_in[1];
  const float* bq    = (const float*)d_in[2];
  const float* Wk    = (const float*)d_in[3];
  const float* bk    = (const float*)d_in[4];
  const float* Wv    = (const float*)d_in[5];
  const float* bv    = (const float*)d_in[6];
  const float* Wo    = (const float*)d_in[7];
  const float* bo    = (const float*)d_in[8];
  const float* gamma = (const float*)d_in[9];
  const float* beta  = (const float*)d_in[10];
  float* out = (float*)d_out;

  char* ws = (char*)d_ws;   // ~114.1 MB used (overlaid layout, see header)
  uint16_t* S    = (uint16_t*)(ws);                 // [0, 64M)
  uint16_t* Xb   = (uint16_t*)(ws);                 // [0, 16M) overlay on S
  uint16_t* Wt   = (uint16_t*)(ws + 67108864);      // [64M, 66M)
  uint16_t* q    = (uint16_t*)(ws + 69206016);      // [66M, 82M), later ctx
  uint16_t* kb   = (uint16_t*)(ws + 85983232);      // [82M, 98M)
  uint16_t* vT   = (uint16_t*)(ws + 102760448);     // [98M, 114M) [8][512][2048]
  float*    rsum = (float*)(ws + 119537664);        // [114M, +64K) fp32[16384]
  uint16_t* ctx  = q;                               // overlay: q dead after scores

  cvt_all_k<<<dim3(8192), dim3(256), 0, stream>>>(X, Xb, Wq, Wk, Wv, Wo, Wt,
                                                  rsum);
  // QKV: M=16384, N=1536, K=512, tile 128x128
  gemm_k<0, 128, 128><<<dim3(12, 128, 1), dim3(256), 0, stream>>>(
      Xb, Wt, (void*)q, kb, vT, nullptr, 512, 512, 512, bq, bk, bv, nullptr,
      1.f);
  // scores: per batch M=N=2048, K=512; E=exp(s/sqrt(512)) + rowsum atomics
  gemm_k<1, 128, 128><<<dim3(16, 16, 8), dim3(256), 0, stream>>>(
      q, kb, (void*)S, nullptr, nullptr, rsum, 512, 512, 512, nullptr, nullptr,
      nullptr, nullptr, 0.044194173824159216f);
  // ctx = (E @ V)/rowsum: per batch M=2048, N=512, K=2048, tile 64x128
  gemm_k<2, 64, 128><<<dim3(4, 32, 8), dim3(256), 0, stream>>>(
      S, vT, (void*)ctx, nullptr, nullptr, rsum, 2048, 2048, 2048, nullptr,
      nullptr, nullptr, nullptr, 1.f);
  // out = ctx @ Wo + bo + X: M=16384, N=512, K=512, tile 128x128
  gemm_k<3, 128, 128><<<dim3(4, 128, 1), dim3(256), 0, stream>>>(
      ctx, Wt + 1536 * 512, (void*)out, nullptr, nullptr, nullptr, 512, 512,
      512, bo, nullptr, nullptr, X, 1.f);
  ln_k<<<dim3(4096), dim3(256), 0, stream>>>(out, gamma, beta);
}